// Round 1
// 377.736 us; speedup vs baseline: 1.1019x; 1.1019x over previous
//
#include <hip/hip_runtime.h>
#include <hip/hip_bf16.h>
#include <math.h>

// BezierDeformableAttention on MI355X (gfx950).
// Shapes: B=4 N=900 D=256 C=256 H=W=200, HEADS=8 PTS=4 K=10, hd=32.
// I/O dtype: float32. Internals: bf16 MFMA, f32 accumulate.
//
// R6 changes vs R5 (416 us):
//  - transpose_bev deleted: f32->bf16 transpose fused into v-GEMM B-staging
//    (reg-stage bev rows, v_cvt_pk_bf16_f32 k-pair packing, chunk-XOR-swizzled
//    LDS so ds_read_b128 fragments stay 16B-aligned).  Saves 82MB W + 82MB R.
//  - epilogue algebra: out = attn@(Wmo*Wo) + q@Wo + (bmo*Wo+bo). Wmoo/bias
//    folded in prep (f32); final = ONE K=512 GEMM over [attn | q_bf16].
//  - head algebra: oa = qin@(Wq*Woa) + (bq*Woa + boa) -> q-GEMM and oa-GEMM
//    fuse into one N=352 split-output GEMM (bf16 cols<256, f32 cols>=256).
//  - 8 launches -> 5.

typedef unsigned short u16;
typedef unsigned int u32;
typedef short bf16x8 __attribute__((ext_vector_type(8)));
typedef float f32x4 __attribute__((ext_vector_type(4)));

__device__ __forceinline__ float bflo(u32 w) {  // low bf16 of packed word
  union { u32 i; float f; } c; c.i = w << 16; return c.f;
}
__device__ __forceinline__ float bfhi(u32 w) {  // high bf16 of packed word
  union { u32 i; float f; } c; c.i = w & 0xffff0000u; return c.f;
}
__device__ __forceinline__ u16 f2bf(float f) {  // RNE
  union { float f; u32 i; } c; c.f = f;
  u32 u = c.i;
  return (u16)((u + 0x7FFFu + ((u >> 16) & 1u)) >> 16);
}
__device__ __forceinline__ int imin(int a, int b) { return a < b ? a : b; }
__device__ __forceinline__ int imax(int a, int b) { return a > b ? a : b; }

__device__ __forceinline__ void glds16(const u16* g, u16* l) {
  __builtin_amdgcn_global_load_lds(
      (__attribute__((address_space(1))) const void*)g,
      (__attribute__((address_space(3))) void*)l, 16, 0, 0);
}

// ------------------------------------------------ weights prep + q conversion
// Builds: qin (bf16 query), wvT, bqoaT = [Wq^T ; (Wq@Woa)^T] (352x256),
// woCat[n][k] = k<256 ? (Wmo@Wo)[k][n] : Wo[k-256][n]  (256x512),
// bcat = [bq | bq@Woa + boa] (352), bprime = bmo@Wo + bo (256).
__global__ __launch_bounds__(256) void prep_weights(
    const float* __restrict__ Wq, const float* __restrict__ Wv,
    const float* __restrict__ Woff, const float* __restrict__ Wattn,
    const float* __restrict__ Wmo, const float* __restrict__ Wo,
    const float* __restrict__ bq, const float* __restrict__ boff,
    const float* __restrict__ battn, const float* __restrict__ bmo,
    const float* __restrict__ bo, const float* __restrict__ query,
    u16* __restrict__ bqoaT, u16* __restrict__ wvT, u16* __restrict__ woCat,
    float* __restrict__ bcat, float* __restrict__ bprime,
    u16* __restrict__ qin)
{
  const int idx = blockIdx.x * 256 + threadIdx.x;
  { // query f32 -> bf16, 921600 elems = 230400 threads x 4
    int i = idx * 4;
    float4 v = *(const float4*)(query + i);
    uint2 st;
    st.x = (u32)f2bf(v.x) | ((u32)f2bf(v.y) << 16);
    st.y = (u32)f2bf(v.z) | ((u32)f2bf(v.w) << 16);
    *(uint2*)(qin + i) = st;
  }
  if (idx < 65536) {
    int r = idx >> 8, c = idx & 255;  // out[r][c] = in[c][r]
    bqoaT[idx] = f2bf(Wq[c * 256 + r]);
    wvT[idx]   = f2bf(Wv[c * 256 + r]);
  }
  if (idx < 24576) {  // (Wq@Woa)^T : n = idx>>8 in [0,96), k = idx&255
    int n = idx >> 8, k = idx & 255;
    const float* wq = Wq + k * 256;
    float s = 0.f;
    if (n < 64) {
      const float* wo = Woff + n;
#pragma unroll 4
      for (int c = 0; c < 256; c += 4) {
        float4 a = *(const float4*)(wq + c);
        s += a.x * wo[(c + 0) * 64] + a.y * wo[(c + 1) * 64] +
             a.z * wo[(c + 2) * 64] + a.w * wo[(c + 3) * 64];
      }
    } else {
      const float* wa = Wattn + (n - 64);
#pragma unroll 4
      for (int c = 0; c < 256; c += 4) {
        float4 a = *(const float4*)(wq + c);
        s += a.x * wa[(c + 0) * 32] + a.y * wa[(c + 1) * 32] +
             a.z * wa[(c + 2) * 32] + a.w * wa[(c + 3) * 32];
      }
    }
    bqoaT[65536 + idx] = f2bf(s);
  }
  if (idx < 131072) {  // woCat[n][k]
    int n = idx >> 9, k = idx & 511;
    float s;
    if (k >= 256) {
      s = Wo[(size_t)(k - 256) * 256 + n];
    } else {
      const float* wm = Wmo + k * 256;
      const float* wo = Wo + n;
      s = 0.f;
#pragma unroll 4
      for (int c = 0; c < 256; c += 4) {
        float4 a = *(const float4*)(wm + c);
        s += a.x * wo[(c + 0) * 256] + a.y * wo[(c + 1) * 256] +
             a.z * wo[(c + 2) * 256] + a.w * wo[(c + 3) * 256];
      }
    }
    woCat[idx] = f2bf(s);
  }
  if (idx >= 131072 && idx < 131328) {  // bprime = bmo@Wo + bo
    int n = idx - 131072;
    const float* wo = Wo + n;
    float s = bo[n];
    for (int c = 0; c < 256; ++c) s += bmo[c] * wo[c * 256];
    bprime[n] = s;
  }
  if (idx >= 131328 && idx < 131680) {  // bcat = [bq | bq@Woa + boa]
    int n = idx - 131328;
    if (n < 256) {
      bcat[n] = bq[n];
    } else {
      int j = n - 256;
      float s;
      if (j < 64) {
        const float* wo = Woff + j;
        s = boff[j];
        for (int c = 0; c < 256; ++c) s += bq[c] * wo[c * 64];
      } else {
        const float* wa = Wattn + (j - 64);
        s = battn[j - 64];
        for (int c = 0; c < 256; ++c) s += bq[c] * wa[c * 32];
      }
      bcat[n] = s;
    }
  }
}

// ---------------------------------------------------------------- MFMA GEMM
// A (bf16, row-major, lda) x Bt (bf16, [N][K]) -> out.
enum { GM_F32 = 0, GM_SPLIT = 1 };

template <int MODE>
__global__ __launch_bounds__(256) void gemm_bt(
    const u16* __restrict__ A, const u16* __restrict__ Bt,
    const float* __restrict__ bias,
    u16* __restrict__ outb, float* __restrict__ outf,
    int M, int N, int K, int lda, int ldo)
{
  __shared__ __align__(16) u16 lA[128 * 32];
  __shared__ __align__(16) u16 lB[128 * 32];
  const int tid = threadIdx.x;
  const int wv = tid >> 6, lane = tid & 63;
  const int m0 = blockIdx.y * 128;
  const int n0 = blockIdx.x * 128;

  const int crow = lane >> 2;
  const int ckoff = (lane & 3) * 8;
  const int a1 = imin(m0 + wv * 16 + crow, M - 1);
  const int a2 = imin(m0 + (wv + 4) * 16 + crow, M - 1);
  const int b1 = imin(n0 + wv * 16 + crow, N - 1);
  const int b2 = imin(n0 + (wv + 4) * 16 + crow, N - 1);
  const u16* gA1 = A + (size_t)a1 * lda + ckoff;
  const u16* gA2 = A + (size_t)a2 * lda + ckoff;
  const u16* gB1 = Bt + (size_t)b1 * K + ckoff;
  const u16* gB2 = Bt + (size_t)b2 * K + ckoff;
  u16* lA1 = lA + wv * 512;  u16* lA2 = lA + (wv + 4) * 512;
  u16* lB1 = lB + wv * 512;  u16* lB2 = lB + (wv + 4) * 512;

  const int fm = (wv & 1) * 64, fn = (wv >> 1) * 64;
  const int fr = lane & 15, fk = (lane >> 4) * 8;

  f32x4 acc[4][4];
#pragma unroll
  for (int i = 0; i < 4; ++i)
#pragma unroll
    for (int j = 0; j < 4; ++j) acc[i][j] = (f32x4){0.f, 0.f, 0.f, 0.f};

  for (int k0 = 0; k0 < K; k0 += 32) {
    glds16(gA1 + k0, lA1);
    glds16(gA2 + k0, lA2);
    glds16(gB1 + k0, lB1);
    glds16(gB2 + k0, lB2);
    __syncthreads();
    bf16x8 af[4], bfv[4];
#pragma unroll
    for (int i = 0; i < 4; ++i)
      af[i] = *(const bf16x8*)&lA[(fm + i * 16 + fr) * 32 + fk];
#pragma unroll
    for (int j = 0; j < 4; ++j)
      bfv[j] = *(const bf16x8*)&lB[(fn + j * 16 + fr) * 32 + fk];
    __syncthreads();
#pragma unroll
    for (int i = 0; i < 4; ++i)
#pragma unroll
      for (int j = 0; j < 4; ++j)
        acc[i][j] = __builtin_amdgcn_mfma_f32_16x16x32_bf16(af[i], bfv[j], acc[i][j], 0, 0, 0);
  }

  // epilogue: C/D layout col=lane&15, row=(lane>>4)*4+reg  [measured m89/m91]
  const int quad = lane >> 4;
#pragma unroll
  for (int j = 0; j < 4; ++j) {
    const int n = n0 + fn + j * 16 + fr;
    const bool nok = (n < N);
    const float bcol = bias[nok ? n : 0];
#pragma unroll
    for (int i = 0; i < 4; ++i) {
      const int mb = m0 + fm + i * 16 + quad * 4;
#pragma unroll
      for (int r = 0; r < 4; ++r) {
        const int m = mb + r;
        if (m < M && nok) {
          float x = acc[i][j][r] + bcol;
          if (MODE == GM_F32) {
            outf[(size_t)m * ldo + n] = x;
          } else {  // GM_SPLIT: n<256 -> bf16 @ stride 512, else f32 @ stride 96
            if (n < 256) outb[(size_t)m * 512 + n] = f2bf(x);
            else outf[(size_t)m * 96 + (n - 256)] = x;
          }
        }
      }
    }
  }
}

// ------------------------------------------- fused transpose + v projection
// v(b,h,hw,32) = bev(b,c,hw)^T @ Wv + bv, bf16 out. A = wvT (256x256 bf16,
// glds16-staged). B staged from f32 bev: thread t = (k-pair kp = t>>4,
// n-block nb = t&15); loads 2 c-rows x 8 cols, packs k-pairs via
// v_cvt_pk_bf16_f32, writes u32 into [n][k] LDS with chunk-XOR swizzle
// (phys_chunk = (k>>3) ^ ((n>>3)&3)) so frag ds_read_b128 stays 16B-aligned
// and writes are <=4-way conflicted (vs 16-way unswizzled).
__global__ __launch_bounds__(256) void gemm_v(
    const u16* __restrict__ A,      // wvT (256x256)
    const float* __restrict__ bev,  // (4,256,40000) f32
    const float* __restrict__ bias, // bv (256)
    u16* __restrict__ outb)         // (4,8,40000,32)
{
  __shared__ __align__(16) u16 lA[128 * 32];
  __shared__ __align__(16) u16 lB[128 * 32];
  const int tid = threadIdx.x;
  const int wv = tid >> 6, lane = tid & 63;
  const int m0 = blockIdx.x * 128;   // 0 or 128 (x fastest: m-pairs adjacent)
  const int n0 = blockIdx.y * 128;
  const int z = blockIdx.z;

  const int crow = lane >> 2, ckoff = (lane & 3) * 8;
  const u16* gA1 = A + (size_t)(m0 + wv * 16 + crow) * 256 + ckoff;
  const u16* gA2 = A + (size_t)(m0 + (wv + 4) * 16 + crow) * 256 + ckoff;
  u16* lA1 = lA + wv * 512;  u16* lA2 = lA + (wv + 4) * 512;

  const int kp = tid >> 4, nb = tid & 15;
  const int cb = imin(n0 + nb * 8, 40000 - 8);
  const float* src = bev + ((size_t)z * 256 + 2 * kp) * 40000 + cb;
  const int wslot = (((kp >> 2) ^ (nb & 3)) << 2) + (kp & 3);  // phys u32 slot
  u32* lBw = (u32*)lB;
  const int wrow = nb * 8;

  const int fm = (wv & 1) * 64, fn = (wv >> 1) * 64;
  const int fr = lane & 15, fk = (lane >> 4) * 8;

  f32x4 acc[4][4];
#pragma unroll
  for (int i = 0; i < 4; ++i)
#pragma unroll
    for (int j = 0; j < 4; ++j) acc[i][j] = (f32x4){0.f, 0.f, 0.f, 0.f};

  float4 r0 = *(const float4*)(src);
  float4 r1 = *(const float4*)(src + 4);
  float4 r2 = *(const float4*)(src + 40000);
  float4 r3 = *(const float4*)(src + 40004);

  for (int k0 = 0; k0 < 256; k0 += 32) {
    glds16(gA1 + k0, lA1);
    glds16(gA2 + k0, lA2);
    // convert + transposed write of current B regs (low=row 2kp, hi=row 2kp+1)
#define CVW(nn, a, b)                                                        \
    { u32 pk;                                                                \
      asm("v_cvt_pk_bf16_f32 %0, %1, %2" : "=v"(pk) : "v"(a), "v"(b));       \
      lBw[(wrow + (nn)) * 16 + wslot] = pk; }
    CVW(0, r0.x, r2.x) CVW(1, r0.y, r2.y) CVW(2, r0.z, r2.z) CVW(3, r0.w, r2.w)
    CVW(4, r1.x, r3.x) CVW(5, r1.y, r3.y) CVW(6, r1.z, r3.z) CVW(7, r1.w, r3.w)
#undef CVW
    if (k0 < 224) {  // prefetch next K-slab (guard: z=3,k0=224 would run OOB)
      const float* s2 = src + (size_t)(k0 + 32) * 40000;
      r0 = *(const float4*)(s2);
      r1 = *(const float4*)(s2 + 4);
      r2 = *(const float4*)(s2 + 40000);
      r3 = *(const float4*)(s2 + 40004);
    }
    __syncthreads();
    bf16x8 af[4], bfv[4];
#pragma unroll
    for (int i = 0; i < 4; ++i)
      af[i] = *(const bf16x8*)&lA[(fm + i * 16 + fr) * 32 + fk];
#pragma unroll
    for (int j = 0; j < 4; ++j) {
      const int n = fn + j * 16 + fr;
      const int pc = (((lane >> 4) ^ ((n >> 3) & 3)) << 3);
      bfv[j] = *(const bf16x8*)&lB[n * 32 + pc];
    }
    __syncthreads();
#pragma unroll
    for (int i = 0; i < 4; ++i)
#pragma unroll
      for (int j = 0; j < 4; ++j)
        acc[i][j] = __builtin_amdgcn_mfma_f32_16x16x32_bf16(af[i], bfv[j], acc[i][j], 0, 0, 0);
  }

  const int quad = lane >> 4;
#pragma unroll
  for (int j = 0; j < 4; ++j) {
    const int n = n0 + fn + j * 16 + fr;
    if (n < 40000) {
#pragma unroll
      for (int i = 0; i < 4; ++i) {
        const int mb = m0 + fm + i * 16 + quad * 4;
        u16 u0 = f2bf(acc[i][j][0] + bias[mb + 0]);
        u16 u1 = f2bf(acc[i][j][1] + bias[mb + 1]);
        u16 u2 = f2bf(acc[i][j][2] + bias[mb + 2]);
        u16 u3 = f2bf(acc[i][j][3] + bias[mb + 3]);
        size_t off = (size_t)z * (8ull * 40000 * 32) +
                     (size_t)(mb >> 5) * (40000 * 32) + (size_t)n * 32 + (mb & 31);
        uint2 st; st.x = (u32)u0 | ((u32)u1 << 16); st.y = (u32)u2 | ((u32)u3 << 16);
        *(uint2*)(outb + off) = st;
      }
    }
  }
}

// ---------------------------------------------------------------- sampler
// One wave per (b,n,h). Lane = (sample-group s = lane>>3) x (chgrp = lane&7).
// Each lane: 4 channels (uint2 = 8B) per corner; 5 passes x 8 samples = 40.
// Cross-lane shfl_xor reduce over the 8 sample-groups at the end.
// Output row stride 512 (cols 0..255 of qcat).
__global__ __launch_bounds__(256) void sampler(
    const float* __restrict__ ctrl,  // (3600,4,2) f32
    const float* __restrict__ pc,    // (6,) f32
    const float* __restrict__ oa_,   // (3600,96) f32: [0:64) off, [64:96) attn
    const u16* __restrict__ v,       // (B,8,40000,32) bf16
    u16* __restrict__ attn_out)      // qcat (3600,512) bf16, cols [0,256)
{
  __shared__ int   sX0[4][40], sY0[4][40];
  __shared__ float sWx[4][40], sWy[4][40], sAw[4][40];
  const int w = threadIdx.x >> 6, lane = threadIdx.x & 63;
  const int bh = blockIdx.x & 31;          // (b*8+h)
  const int n = (blockIdx.x >> 5) * 4 + w; // 225*4 = 900
  const int h = bh & 7, b = bh >> 3;
  const int row = b * 900 + n;

  if (lane < 40) {
    const int k = lane >> 2, p = lane & 3;
    const float t = (float)k * (1.0f / 9.0f), u = 1.f - t;
    const float c0 = u * u * u, c1 = 3.f * u * u * t, c2 = 3.f * u * t * t, c3 = t * t * t;
    const float* cp = ctrl + (size_t)row * 8;
    float cx = c0 * cp[0] + c1 * cp[2] + c2 * cp[4] + c3 * cp[6];
    float cy = c0 * cp[1] + c1 * cp[3] + c2 * cp[5] + c3 * cp[7];
    float nx = (cx - pc[0]) / (pc[3] - pc[0]);
    float ny = (cy - pc[1]) / (pc[4] - pc[1]);
    nx = fminf(fmaxf(nx, 0.01f), 0.99f);
    ny = fminf(fmaxf(ny, 0.01f), 0.99f);
    const float* oa = oa_ + (size_t)row * 96;
    float ox = oa[h * 8 + p * 2 + 0], oy = oa[h * 8 + p * 2 + 1];
    float l0 = oa[64 + h * 4 + 0], l1 = oa[64 + h * 4 + 1];
    float l2 = oa[64 + h * 4 + 2], l3 = oa[64 + h * 4 + 3];
    float mx = fmaxf(fmaxf(l0, l1), fmaxf(l2, l3));
    float e0 = __expf(l0 - mx), e1 = __expf(l1 - mx), e2 = __expf(l2 - mx), e3 = __expf(l3 - mx);
    float lp = (p == 0) ? l0 : (p == 1) ? l1 : (p == 2) ? l2 : l3;
    float aw = __expf(lp - mx) / (e0 + e1 + e2 + e3);
    float gx = (nx + ox * (1.f / 200.f)) * 200.f - 0.5f;
    float gy = (ny + oy * (1.f / 200.f)) * 200.f - 0.5f;
    float x0 = floorf(gx), y0 = floorf(gy);
    sX0[w][lane] = (int)x0; sY0[w][lane] = (int)y0;
    sWx[w][lane] = gx - x0; sWy[w][lane] = gy - y0; sAw[w][lane] = aw;
  }
  __syncthreads();

  const int sg = lane >> 3;        // sample group 0..7
  const int ch0 = (lane & 7) * 4;  // 4 channels
  const u16* vb = v + ((size_t)(b * 8 + h)) * (40000 * 32) + ch0;
  float a0 = 0.f, a1 = 0.f, a2 = 0.f, a3 = 0.f;
#pragma unroll
  for (int p = 0; p < 5; ++p) {
    const int s = p * 8 + sg;
    const int x0 = sX0[w][s], y0 = sY0[w][s];
    const float wx = sWx[w][s], wy = sWy[w][s], aw = sAw[w][s];
    const int x1 = x0 + 1, y1 = y0 + 1;
    const int cx0 = imin(imax(x0, 0), 199), cx1 = imin(imax(x1, 0), 199);
    const int cy0 = imin(imax(y0, 0), 199), cy1 = imin(imax(y1, 0), 199);
    const bool vx0 = (u32)x0 < 200u, vx1 = (u32)x1 < 200u;
    const bool vy0 = (u32)y0 < 200u, vy1 = (u32)y1 < 200u;
    const float w00 = (vx0 && vy0) ? aw * (1.f - wx) * (1.f - wy) : 0.f;
    const float w10 = (vx1 && vy0) ? aw * wx * (1.f - wy) : 0.f;
    const float w01 = (vx0 && vy1) ? aw * (1.f - wx) * wy : 0.f;
    const float w11 = (vx1 && vy1) ? aw * wx * wy : 0.f;
    uint2 d00 = *(const uint2*)(vb + (size_t)(cy0 * 200 + cx0) * 32);
    uint2 d10 = *(const uint2*)(vb + (size_t)(cy0 * 200 + cx1) * 32);
    uint2 d01 = *(const uint2*)(vb + (size_t)(cy1 * 200 + cx0) * 32);
    uint2 d11 = *(const uint2*)(vb + (size_t)(cy1 * 200 + cx1) * 32);
    a0 += w00 * bflo(d00.x) + w10 * bflo(d10.x) + w01 * bflo(d01.x) + w11 * bflo(d11.x);
    a1 += w00 * bfhi(d00.x) + w10 * bfhi(d10.x) + w01 * bfhi(d01.x) + w11 * bfhi(d11.x);
    a2 += w00 * bflo(d00.y) + w10 * bflo(d10.y) + w01 * bflo(d01.y) + w11 * bflo(d11.y);
    a3 += w00 * bfhi(d00.y) + w10 * bfhi(d10.y) + w01 * bfhi(d01.y) + w11 * bfhi(d11.y);
  }
#pragma unroll
  for (int off = 8; off < 64; off <<= 1) {
    a0 += __shfl_xor(a0, off);
    a1 += __shfl_xor(a1, off);
    a2 += __shfl_xor(a2, off);
    a3 += __shfl_xor(a3, off);
  }
  if (lane < 8) {
    uint2 st;
    st.x = (u32)f2bf(a0) | ((u32)f2bf(a1) << 16);
    st.y = (u32)f2bf(a2) | ((u32)f2bf(a3) << 16);
    *(uint2*)(attn_out + (size_t)row * 512 + h * 32 + ch0) = st;
  }
}

// ---------------------------------------------------------------- launch
extern "C" void kernel_launch(void* const* d_in, const int* in_sizes, int n_in,
                              void* d_out, int out_size, void* d_ws, size_t ws_size,
                              hipStream_t stream)
{
  const float* query = (const float*)d_in[0];
  const float* ctrl  = (const float*)d_in[1];
  const float* bev   = (const float*)d_in[2];
  // d_in[3] spatial_shapes int32 (=200,200) hardcoded
  const float* pc    = (const float*)d_in[4];
  const float* Wq    = (const float*)d_in[5];  const float* bq    = (const float*)d_in[6];
  const float* Wv    = (const float*)d_in[7];  const float* bv    = (const float*)d_in[8];
  const float* Woff  = (const float*)d_in[9];  const float* boff  = (const float*)d_in[10];
  const float* Wattn = (const float*)d_in[11]; const float* battn = (const float*)d_in[12];
  const float* Wmo   = (const float*)d_in[13]; const float* bmo   = (const float*)d_in[14];
  const float* Wo    = (const float*)d_in[15]; const float* bo    = (const float*)d_in[16];

  char* ws = (char*)d_ws;
  size_t off = 0;
  auto alloc = [&](size_t bytes) -> void* {
    void* p = ws + off; off += (bytes + 255) & ~(size_t)255; return p;
  };
  u16*  v     = (u16*)alloc(4ull * 8 * 40000 * 32 * 2); // 81.92 MB
  u16*  qin   = (u16*)alloc(3600ull * 256 * 2);
  u16*  wvT   = (u16*)alloc(65536 * 2);
  u16*  bqoaT = (u16*)alloc(352 * 256 * 2);
  u16*  woCat = (u16*)alloc(256 * 512 * 2);
  float* bcat = (float*)alloc(352 * 4);
  float* bprime = (float*)alloc(256 * 4);
  float* oaf  = (float*)alloc(3600ull * 96 * 4);
  u16*  qcat  = (u16*)alloc(3600ull * 512 * 2);  // [attn | q_bf16]
  (void)ws_size; (void)in_sizes; (void)n_in; (void)out_size;

  prep_weights<<<900, 256, 0, stream>>>(Wq, Wv, Woff, Wattn, Wmo, Wo,
                                        bq, boff, battn, bmo, bo, query,
                                        bqoaT, wvT, woCat, bcat, bprime, qin);
  gemm_v<<<dim3(2, 313, 4), 256, 0, stream>>>(wvT, bev, bv, v);
  gemm_bt<GM_SPLIT><<<dim3(3, 29), 256, 0, stream>>>(
      qin, bqoaT, bcat, qcat + 256, oaf, 3600, 352, 256, 256, 0);
  sampler<<<7200, 256, 0, stream>>>(ctrl, pc, oaf, v, qcat);
  gemm_bt<GM_F32><<<dim3(2, 29), 256, 0, stream>>>(
      qcat, woCat, bprime, nullptr, (float*)d_out, 3600, 256, 512, 512, 256);
}

// Round 2
// 376.214 us; speedup vs baseline: 1.1063x; 1.0040x over previous
//
#include <hip/hip_runtime.h>
#include <hip/hip_bf16.h>
#include <math.h>

// BezierDeformableAttention on MI355X (gfx950).
// Shapes: B=4 N=900 D=256 C=256 H=W=200, HEADS=8 PTS=4 K=10, hd=32.
// I/O dtype: float32. Internals: bf16 MFMA, f32 accumulate.
//
// R7 changes vs R6 (377.7 us; gemm_v = 97.7 us @ 31% HBM, 8% MFMA):
//  - gemm_v restructured T3/T4-style: __syncthreads (which drains vmcnt(0)
//    every slab, serializing HBM latency) replaced by raw s_barrier +
//    s_waitcnt lgkmcnt(0). B prefetch loads now stay in flight across the
//    barrier (consumed by v_cvt_pk one iteration later).
//  - A panel staged ONCE in prologue (8 slabs, 64 KB LDS, conflict-free
//    per-slab layout); B double-buffered (2 x 8 KB) -> ONE barrier per slab.
//  - sched_barrier(0) + "memory" fences around waits (rule #18); static
//    two-reg-set swap under full unroll (rule #20). LDS 80 KB -> 2 blocks/CU.

typedef unsigned short u16;
typedef unsigned int u32;
typedef short bf16x8 __attribute__((ext_vector_type(8)));
typedef float f32x4 __attribute__((ext_vector_type(4)));

__device__ __forceinline__ float bflo(u32 w) {  // low bf16 of packed word
  union { u32 i; float f; } c; c.i = w << 16; return c.f;
}
__device__ __forceinline__ float bfhi(u32 w) {  // high bf16 of packed word
  union { u32 i; float f; } c; c.i = w & 0xffff0000u; return c.f;
}
__device__ __forceinline__ u16 f2bf(float f) {  // RNE
  union { float f; u32 i; } c; c.f = f;
  u32 u = c.i;
  return (u16)((u + 0x7FFFu + ((u >> 16) & 1u)) >> 16);
}
__device__ __forceinline__ int imin(int a, int b) { return a < b ? a : b; }
__device__ __forceinline__ int imax(int a, int b) { return a > b ? a : b; }

__device__ __forceinline__ void glds16(const u16* g, u16* l) {
  __builtin_amdgcn_global_load_lds(
      (__attribute__((address_space(1))) const void*)g,
      (__attribute__((address_space(3))) void*)l, 16, 0, 0);
}

// ------------------------------------------------ weights prep + q conversion
// Builds: qin (bf16 query), wvT, bqoaT = [Wq^T ; (Wq@Woa)^T] (352x256),
// woCat[n][k] = k<256 ? (Wmo@Wo)[k][n] : Wo[k-256][n]  (256x512),
// bcat = [bq | bq@Woa + boa] (352), bprime = bmo@Wo + bo (256).
__global__ __launch_bounds__(256) void prep_weights(
    const float* __restrict__ Wq, const float* __restrict__ Wv,
    const float* __restrict__ Woff, const float* __restrict__ Wattn,
    const float* __restrict__ Wmo, const float* __restrict__ Wo,
    const float* __restrict__ bq, const float* __restrict__ boff,
    const float* __restrict__ battn, const float* __restrict__ bmo,
    const float* __restrict__ bo, const float* __restrict__ query,
    u16* __restrict__ bqoaT, u16* __restrict__ wvT, u16* __restrict__ woCat,
    float* __restrict__ bcat, float* __restrict__ bprime,
    u16* __restrict__ qin)
{
  const int idx = blockIdx.x * 256 + threadIdx.x;
  { // query f32 -> bf16, 921600 elems = 230400 threads x 4
    int i = idx * 4;
    float4 v = *(const float4*)(query + i);
    uint2 st;
    st.x = (u32)f2bf(v.x) | ((u32)f2bf(v.y) << 16);
    st.y = (u32)f2bf(v.z) | ((u32)f2bf(v.w) << 16);
    *(uint2*)(qin + i) = st;
  }
  if (idx < 65536) {
    int r = idx >> 8, c = idx & 255;  // out[r][c] = in[c][r]
    bqoaT[idx] = f2bf(Wq[c * 256 + r]);
    wvT[idx]   = f2bf(Wv[c * 256 + r]);
  }
  if (idx < 24576) {  // (Wq@Woa)^T : n = idx>>8 in [0,96), k = idx&255
    int n = idx >> 8, k = idx & 255;
    const float* wq = Wq + k * 256;
    float s = 0.f;
    if (n < 64) {
      const float* wo = Woff + n;
#pragma unroll 4
      for (int c = 0; c < 256; c += 4) {
        float4 a = *(const float4*)(wq + c);
        s += a.x * wo[(c + 0) * 64] + a.y * wo[(c + 1) * 64] +
             a.z * wo[(c + 2) * 64] + a.w * wo[(c + 3) * 64];
      }
    } else {
      const float* wa = Wattn + (n - 64);
#pragma unroll 4
      for (int c = 0; c < 256; c += 4) {
        float4 a = *(const float4*)(wq + c);
        s += a.x * wa[(c + 0) * 32] + a.y * wa[(c + 1) * 32] +
             a.z * wa[(c + 2) * 32] + a.w * wa[(c + 3) * 32];
      }
    }
    bqoaT[65536 + idx] = f2bf(s);
  }
  if (idx < 131072) {  // woCat[n][k]
    int n = idx >> 9, k = idx & 511;
    float s;
    if (k >= 256) {
      s = Wo[(size_t)(k - 256) * 256 + n];
    } else {
      const float* wm = Wmo + k * 256;
      const float* wo = Wo + n;
      s = 0.f;
#pragma unroll 4
      for (int c = 0; c < 256; c += 4) {
        float4 a = *(const float4*)(wm + c);
        s += a.x * wo[(c + 0) * 256] + a.y * wo[(c + 1) * 256] +
             a.z * wo[(c + 2) * 256] + a.w * wo[(c + 3) * 256];
      }
    }
    woCat[idx] = f2bf(s);
  }
  if (idx >= 131072 && idx < 131328) {  // bprime = bmo@Wo + bo
    int n = idx - 131072;
    const float* wo = Wo + n;
    float s = bo[n];
    for (int c = 0; c < 256; ++c) s += bmo[c] * wo[c * 256];
    bprime[n] = s;
  }
  if (idx >= 131328 && idx < 131680) {  // bcat = [bq | bq@Woa + boa]
    int n = idx - 131328;
    if (n < 256) {
      bcat[n] = bq[n];
    } else {
      int j = n - 256;
      float s;
      if (j < 64) {
        const float* wo = Woff + j;
        s = boff[j];
        for (int c = 0; c < 256; ++c) s += bq[c] * wo[c * 64];
      } else {
        const float* wa = Wattn + (j - 64);
        s = battn[j - 64];
        for (int c = 0; c < 256; ++c) s += bq[c] * wa[c * 32];
      }
      bcat[n] = s;
    }
  }
}

// ---------------------------------------------------------------- MFMA GEMM
// A (bf16, row-major, lda) x Bt (bf16, [N][K]) -> out.
enum { GM_F32 = 0, GM_SPLIT = 1 };

template <int MODE>
__global__ __launch_bounds__(256) void gemm_bt(
    const u16* __restrict__ A, const u16* __restrict__ Bt,
    const float* __restrict__ bias,
    u16* __restrict__ outb, float* __restrict__ outf,
    int M, int N, int K, int lda, int ldo)
{
  __shared__ __align__(16) u16 lA[128 * 32];
  __shared__ __align__(16) u16 lB[128 * 32];
  const int tid = threadIdx.x;
  const int wv = tid >> 6, lane = tid & 63;
  const int m0 = blockIdx.y * 128;
  const int n0 = blockIdx.x * 128;

  const int crow = lane >> 2;
  const int ckoff = (lane & 3) * 8;
  const int a1 = imin(m0 + wv * 16 + crow, M - 1);
  const int a2 = imin(m0 + (wv + 4) * 16 + crow, M - 1);
  const int b1 = imin(n0 + wv * 16 + crow, N - 1);
  const int b2 = imin(n0 + (wv + 4) * 16 + crow, N - 1);
  const u16* gA1 = A + (size_t)a1 * lda + ckoff;
  const u16* gA2 = A + (size_t)a2 * lda + ckoff;
  const u16* gB1 = Bt + (size_t)b1 * K + ckoff;
  const u16* gB2 = Bt + (size_t)b2 * K + ckoff;
  u16* lA1 = lA + wv * 512;  u16* lA2 = lA + (wv + 4) * 512;
  u16* lB1 = lB + wv * 512;  u16* lB2 = lB + (wv + 4) * 512;

  const int fm = (wv & 1) * 64, fn = (wv >> 1) * 64;
  const int fr = lane & 15, fk = (lane >> 4) * 8;

  f32x4 acc[4][4];
#pragma unroll
  for (int i = 0; i < 4; ++i)
#pragma unroll
    for (int j = 0; j < 4; ++j) acc[i][j] = (f32x4){0.f, 0.f, 0.f, 0.f};

  for (int k0 = 0; k0 < K; k0 += 32) {
    glds16(gA1 + k0, lA1);
    glds16(gA2 + k0, lA2);
    glds16(gB1 + k0, lB1);
    glds16(gB2 + k0, lB2);
    __syncthreads();
    bf16x8 af[4], bfv[4];
#pragma unroll
    for (int i = 0; i < 4; ++i)
      af[i] = *(const bf16x8*)&lA[(fm + i * 16 + fr) * 32 + fk];
#pragma unroll
    for (int j = 0; j < 4; ++j)
      bfv[j] = *(const bf16x8*)&lB[(fn + j * 16 + fr) * 32 + fk];
    __syncthreads();
#pragma unroll
    for (int i = 0; i < 4; ++i)
#pragma unroll
      for (int j = 0; j < 4; ++j)
        acc[i][j] = __builtin_amdgcn_mfma_f32_16x16x32_bf16(af[i], bfv[j], acc[i][j], 0, 0, 0);
  }

  // epilogue: C/D layout col=lane&15, row=(lane>>4)*4+reg  [measured m89/m91]
  const int quad = lane >> 4;
#pragma unroll
  for (int j = 0; j < 4; ++j) {
    const int n = n0 + fn + j * 16 + fr;
    const bool nok = (n < N);
    const float bcol = bias[nok ? n : 0];
#pragma unroll
    for (int i = 0; i < 4; ++i) {
      const int mb = m0 + fm + i * 16 + quad * 4;
#pragma unroll
      for (int r = 0; r < 4; ++r) {
        const int m = mb + r;
        if (m < M && nok) {
          float x = acc[i][j][r] + bcol;
          if (MODE == GM_F32) {
            outf[(size_t)m * ldo + n] = x;
          } else {  // GM_SPLIT: n<256 -> bf16 @ stride 512, else f32 @ stride 96
            if (n < 256) outb[(size_t)m * 512 + n] = f2bf(x);
            else outf[(size_t)m * 96 + (n - 256)] = x;
          }
        }
      }
    }
  }
}

// ------------------------------------------- fused transpose + v projection
// v(b,h,hw,32) = bev(b,c,hw)^T @ Wv + bv, bf16 out.
// A = wvT (256x256), staged ONCE into 64 KB LDS (8 slabs, conflict-free
// per-slab layout). B staged from f32 bev per slab: thread t = (k-pair
// kp = t>>4, n-block nb = t&15); v_cvt_pk_bf16_f32 k-pair packing into a
// chunk-XOR-swizzled [n][k] LDS tile, double-buffered (2 x 8 KB).
// Sync: ONE raw s_barrier + s_waitcnt lgkmcnt(0) per slab; vmcnt is never
// drained in the loop so B prefetch loads span the barrier (T3/T4).
#define LOADB(S, R0, R1, R2, R3)                                   \
  { const float* s2_ = src + (size_t)((S) * 32) * 40000;           \
    R0 = *(const float4*)(s2_);                                    \
    R1 = *(const float4*)(s2_ + 4);                                \
    R2 = *(const float4*)(s2_ + 40000);                            \
    R3 = *(const float4*)(s2_ + 40004); }

#define CVW8(BUF, R0, R1, R2, R3)                                            \
  { u32* lbw_ = (u32*)(BUF); u32 pk_;                                        \
    asm("v_cvt_pk_bf16_f32 %0, %1, %2" : "=v"(pk_) : "v"(R0.x), "v"(R2.x)); \
    lbw_[(wrow + 0) * 16 + wslot] = pk_;                                     \
    asm("v_cvt_pk_bf16_f32 %0, %1, %2" : "=v"(pk_) : "v"(R0.y), "v"(R2.y)); \
    lbw_[(wrow + 1) * 16 + wslot] = pk_;                                     \
    asm("v_cvt_pk_bf16_f32 %0, %1, %2" : "=v"(pk_) : "v"(R0.z), "v"(R2.z)); \
    lbw_[(wrow + 2) * 16 + wslot] = pk_;                                     \
    asm("v_cvt_pk_bf16_f32 %0, %1, %2" : "=v"(pk_) : "v"(R0.w), "v"(R2.w)); \
    lbw_[(wrow + 3) * 16 + wslot] = pk_;                                     \
    asm("v_cvt_pk_bf16_f32 %0, %1, %2" : "=v"(pk_) : "v"(R1.x), "v"(R3.x)); \
    lbw_[(wrow + 4) * 16 + wslot] = pk_;                                     \
    asm("v_cvt_pk_bf16_f32 %0, %1, %2" : "=v"(pk_) : "v"(R1.y), "v"(R3.y)); \
    lbw_[(wrow + 5) * 16 + wslot] = pk_;                                     \
    asm("v_cvt_pk_bf16_f32 %0, %1, %2" : "=v"(pk_) : "v"(R1.z), "v"(R3.z)); \
    lbw_[(wrow + 6) * 16 + wslot] = pk_;                                     \
    asm("v_cvt_pk_bf16_f32 %0, %1, %2" : "=v"(pk_) : "v"(R1.w), "v"(R3.w)); \
    lbw_[(wrow + 7) * 16 + wslot] = pk_; }

__global__ __launch_bounds__(256, 2) void gemm_v(
    const u16* __restrict__ A,      // wvT (256x256)
    const float* __restrict__ bev,  // (4,256,40000) f32
    const float* __restrict__ bias, // bv (256)
    u16* __restrict__ outb)         // (4,8,40000,32)
{
  __shared__ __align__(16) u16 lA[8 * 128 * 32];  // 64 KB, slab-major
  __shared__ __align__(16) u16 lB[2][128 * 32];   // 2 x 8 KB double buffer
  const int tid = threadIdx.x;
  const int wv = tid >> 6, lane = tid & 63;
  const int m0 = blockIdx.x * 128;   // x fastest: both m-tiles of a B-panel adjacent
  const int n0 = blockIdx.y * 128;
  const int z = blockIdx.z;

  const int crow = lane >> 2, ckoff = (lane & 3) * 8;
  const u16* gA1 = A + (size_t)(m0 + wv * 16 + crow) * 256 + ckoff;
  const u16* gA2 = A + (size_t)(m0 + (wv + 4) * 16 + crow) * 256 + ckoff;
  u16* lA1 = lA + wv * 512;
  u16* lA2 = lA + (wv + 4) * 512;

  const int kp = tid >> 4, nb = tid & 15;
  const int cb = imin(n0 + nb * 8, 40000 - 8);
  const float* src = bev + ((size_t)z * 256 + 2 * kp) * 40000 + cb;
  const int wslot = (((kp >> 2) ^ (nb & 3)) << 2) + (kp & 3);  // phys u32 slot
  const int wrow = nb * 8;

  const int fm = (wv & 1) * 64, fn = (wv >> 1) * 64;
  const int fr = lane & 15, fk = (lane >> 4) * 8;

  f32x4 acc[4][4];
#pragma unroll
  for (int i = 0; i < 4; ++i)
#pragma unroll
    for (int j = 0; j < 4; ++j) acc[i][j] = (f32x4){0.f, 0.f, 0.f, 0.f};

  float4 ra0, ra1, ra2, ra3, rb0, rb1, rb2, rb3;

  // ---- prologue: slab0 -> regs; A(all 8 slabs) -> LDS; slab0 -> buf0;
  //      slab1 -> regs; drain A+buf0 (vmcnt(4) leaves slab1 in flight).
  LOADB(0, ra0, ra1, ra2, ra3);
#pragma unroll
  for (int s = 0; s < 8; ++s) {
    glds16(gA1 + s * 32, lA1 + s * 4096);
    glds16(gA2 + s * 32, lA2 + s * 4096);
  }
  asm volatile("" ::: "memory");
  CVW8(lB[0], ra0, ra1, ra2, ra3);
  asm volatile("" ::: "memory");
  LOADB(1, rb0, rb1, rb2, rb3);
  __builtin_amdgcn_sched_barrier(0);
  asm volatile("s_waitcnt vmcnt(4) lgkmcnt(0)" ::: "memory");
  __builtin_amdgcn_sched_barrier(0);
  __builtin_amdgcn_s_barrier();
  __builtin_amdgcn_sched_barrier(0);

  // ---- main loop: 8 slabs, ONE barrier each, vmcnt never drained.
#pragma unroll
  for (int t = 0; t < 8; ++t) {
    bf16x8 af[4], bfv[4];
#pragma unroll
    for (int i = 0; i < 4; ++i)
      af[i] = *(const bf16x8*)&lA[t * 4096 + (fm + i * 16 + fr) * 32 + fk];
#pragma unroll
    for (int j = 0; j < 4; ++j) {
      const int n = fn + j * 16 + fr;
      const int pc = (((lane >> 4) ^ ((n >> 3) & 3)) << 3);
      bfv[j] = *(const bf16x8*)&lB[t & 1][n * 32 + pc];
    }
    if (t < 7) {  // stage slab t+1 into the other buffer (regs loaded 1 iter ago)
      if ((t & 1) == 0) { CVW8(lB[1], rb0, rb1, rb2, rb3); }
      else              { CVW8(lB[0], ra0, ra1, ra2, ra3); }
    }
    if (t < 6) {  // issue loads for slab t+2 (in flight across the barrier)
      if ((t & 1) == 0) { LOADB(t + 2, ra0, ra1, ra2, ra3); }
      else              { LOADB(t + 2, rb0, rb1, rb2, rb3); }
    }
#pragma unroll
    for (int i = 0; i < 4; ++i)
#pragma unroll
      for (int j = 0; j < 4; ++j)
        acc[i][j] = __builtin_amdgcn_mfma_f32_16x16x32_bf16(af[i], bfv[j], acc[i][j], 0, 0, 0);
    if (t < 7) {
      __builtin_amdgcn_sched_barrier(0);
      asm volatile("s_waitcnt lgkmcnt(0)" ::: "memory");
      __builtin_amdgcn_sched_barrier(0);
      __builtin_amdgcn_s_barrier();
      __builtin_amdgcn_sched_barrier(0);
    }
  }

  const int quad = lane >> 4;
#pragma unroll
  for (int j = 0; j < 4; ++j) {
    const int n = n0 + fn + j * 16 + fr;
    if (n < 40000) {
#pragma unroll
      for (int i = 0; i < 4; ++i) {
        const int mb = m0 + fm + i * 16 + quad * 4;
        u16 u0 = f2bf(acc[i][j][0] + bias[mb + 0]);
        u16 u1 = f2bf(acc[i][j][1] + bias[mb + 1]);
        u16 u2 = f2bf(acc[i][j][2] + bias[mb + 2]);
        u16 u3 = f2bf(acc[i][j][3] + bias[mb + 3]);
        size_t off = (size_t)z * (8ull * 40000 * 32) +
                     (size_t)(mb >> 5) * (40000 * 32) + (size_t)n * 32 + (mb & 31);
        uint2 st; st.x = (u32)u0 | ((u32)u1 << 16); st.y = (u32)u2 | ((u32)u3 << 16);
        *(uint2*)(outb + off) = st;
      }
    }
  }
}

// ---------------------------------------------------------------- sampler
// One wave per (b,n,h). Lane = (sample-group s = lane>>3) x (chgrp = lane&7).
// Each lane: 4 channels (uint2 = 8B) per corner; 5 passes x 8 samples = 40.
// Cross-lane shfl_xor reduce over the 8 sample-groups at the end.
// Output row stride 512 (cols 0..255 of qcat).
__global__ __launch_bounds__(256) void sampler(
    const float* __restrict__ ctrl,  // (3600,4,2) f32
    const float* __restrict__ pc,    // (6,) f32
    const float* __restrict__ oa_,   // (3600,96) f32: [0:64) off, [64:96) attn
    const u16* __restrict__ v,       // (B,8,40000,32) bf16
    u16* __restrict__ attn_out)      // qcat (3600,512) bf16, cols [0,256)
{
  __shared__ int   sX0[4][40], sY0[4][40];
  __shared__ float sWx[4][40], sWy[4][40], sAw[4][40];
  const int w = threadIdx.x >> 6, lane = threadIdx.x & 63;
  const int bh = blockIdx.x & 31;          // (b*8+h)
  const int n = (blockIdx.x >> 5) * 4 + w; // 225*4 = 900
  const int h = bh & 7, b = bh >> 3;
  const int row = b * 900 + n;

  if (lane < 40) {
    const int k = lane >> 2, p = lane & 3;
    const float t = (float)k * (1.0f / 9.0f), u = 1.f - t;
    const float c0 = u * u * u, c1 = 3.f * u * u * t, c2 = 3.f * u * t * t, c3 = t * t * t;
    const float* cp = ctrl + (size_t)row * 8;
    float cx = c0 * cp[0] + c1 * cp[2] + c2 * cp[4] + c3 * cp[6];
    float cy = c0 * cp[1] + c1 * cp[3] + c2 * cp[5] + c3 * cp[7];
    float nx = (cx - pc[0]) / (pc[3] - pc[0]);
    float ny = (cy - pc[1]) / (pc[4] - pc[1]);
    nx = fminf(fmaxf(nx, 0.01f), 0.99f);
    ny = fminf(fmaxf(ny, 0.01f), 0.99f);
    const float* oa = oa_ + (size_t)row * 96;
    float ox = oa[h * 8 + p * 2 + 0], oy = oa[h * 8 + p * 2 + 1];
    float l0 = oa[64 + h * 4 + 0], l1 = oa[64 + h * 4 + 1];
    float l2 = oa[64 + h * 4 + 2], l3 = oa[64 + h * 4 + 3];
    float mx = fmaxf(fmaxf(l0, l1), fmaxf(l2, l3));
    float e0 = __expf(l0 - mx), e1 = __expf(l1 - mx), e2 = __expf(l2 - mx), e3 = __expf(l3 - mx);
    float lp = (p == 0) ? l0 : (p == 1) ? l1 : (p == 2) ? l2 : l3;
    float aw = __expf(lp - mx) / (e0 + e1 + e2 + e3);
    float gx = (nx + ox * (1.f / 200.f)) * 200.f - 0.5f;
    float gy = (ny + oy * (1.f / 200.f)) * 200.f - 0.5f;
    float x0 = floorf(gx), y0 = floorf(gy);
    sX0[w][lane] = (int)x0; sY0[w][lane] = (int)y0;
    sWx[w][lane] = gx - x0; sWy[w][lane] = gy - y0; sAw[w][lane] = aw;
  }
  __syncthreads();

  const int sg = lane >> 3;        // sample group 0..7
  const int ch0 = (lane & 7) * 4;  // 4 channels
  const u16* vb = v + ((size_t)(b * 8 + h)) * (40000 * 32) + ch0;
  float a0 = 0.f, a1 = 0.f, a2 = 0.f, a3 = 0.f;
#pragma unroll
  for (int p = 0; p < 5; ++p) {
    const int s = p * 8 + sg;
    const int x0 = sX0[w][s], y0 = sY0[w][s];
    const float wx = sWx[w][s], wy = sWy[w][s], aw = sAw[w][s];
    const int x1 = x0 + 1, y1 = y0 + 1;
    const int cx0 = imin(imax(x0, 0), 199), cx1 = imin(imax(x1, 0), 199);
    const int cy0 = imin(imax(y0, 0), 199), cy1 = imin(imax(y1, 0), 199);
    const bool vx0 = (u32)x0 < 200u, vx1 = (u32)x1 < 200u;
    const bool vy0 = (u32)y0 < 200u, vy1 = (u32)y1 < 200u;
    const float w00 = (vx0 && vy0) ? aw * (1.f - wx) * (1.f - wy) : 0.f;
    const float w10 = (vx1 && vy0) ? aw * wx * (1.f - wy) : 0.f;
    const float w01 = (vx0 && vy1) ? aw * (1.f - wx) * wy : 0.f;
    const float w11 = (vx1 && vy1) ? aw * wx * wy : 0.f;
    uint2 d00 = *(const uint2*)(vb + (size_t)(cy0 * 200 + cx0) * 32);
    uint2 d10 = *(const uint2*)(vb + (size_t)(cy0 * 200 + cx1) * 32);
    uint2 d01 = *(const uint2*)(vb + (size_t)(cy1 * 200 + cx0) * 32);
    uint2 d11 = *(const uint2*)(vb + (size_t)(cy1 * 200 + cx1) * 32);
    a0 += w00 * bflo(d00.x) + w10 * bflo(d10.x) + w01 * bflo(d01.x) + w11 * bflo(d11.x);
    a1 += w00 * bfhi(d00.x) + w10 * bfhi(d10.x) + w01 * bfhi(d01.x) + w11 * bfhi(d11.x);
    a2 += w00 * bflo(d00.y) + w10 * bflo(d10.y) + w01 * bflo(d01.y) + w11 * bflo(d11.y);
    a3 += w00 * bfhi(d00.y) + w10 * bfhi(d10.y) + w01 * bfhi(d01.y) + w11 * bfhi(d11.y);
  }
#pragma unroll
  for (int off = 8; off < 64; off <<= 1) {
    a0 += __shfl_xor(a0, off);
    a1 += __shfl_xor(a1, off);
    a2 += __shfl_xor(a2, off);
    a3 += __shfl_xor(a3, off);
  }
  if (lane < 8) {
    uint2 st;
    st.x = (u32)f2bf(a0) | ((u32)f2bf(a1) << 16);
    st.y = (u32)f2bf(a2) | ((u32)f2bf(a3) << 16);
    *(uint2*)(attn_out + (size_t)row * 512 + h * 32 + ch0) = st;
  }
}

// ---------------------------------------------------------------- launch
extern "C" void kernel_launch(void* const* d_in, const int* in_sizes, int n_in,
                              void* d_out, int out_size, void* d_ws, size_t ws_size,
                              hipStream_t stream)
{
  const float* query = (const float*)d_in[0];
  const float* ctrl  = (const float*)d_in[1];
  const float* bev   = (const float*)d_in[2];
  // d_in[3] spatial_shapes int32 (=200,200) hardcoded
  const float* pc    = (const float*)d_in[4];
  const float* Wq    = (const float*)d_in[5];  const float* bq    = (const float*)d_in[6];
  const float* Wv    = (const float*)d_in[7];  const float* bv    = (const float*)d_in[8];
  const float* Woff  = (const float*)d_in[9];  const float* boff  = (const float*)d_in[10];
  const float* Wattn = (const float*)d_in[11]; const float* battn = (const float*)d_in[12];
  const float* Wmo   = (const float*)d_in[13]; const float* bmo   = (const float*)d_in[14];
  const float* Wo    = (const float*)d_in[15]; const float* bo    = (const float*)d_in[16];

  char* ws = (char*)d_ws;
  size_t off = 0;
  auto alloc = [&](size_t bytes) -> void* {
    void* p = ws + off; off += (bytes + 255) & ~(size_t)255; return p;
  };
  u16*  v     = (u16*)alloc(4ull * 8 * 40000 * 32 * 2); // 81.92 MB
  u16*  qin   = (u16*)alloc(3600ull * 256 * 2);
  u16*  wvT   = (u16*)alloc(65536 * 2);
  u16*  bqoaT = (u16*)alloc(352 * 256 * 2);
  u16*  woCat = (u16*)alloc(256 * 512 * 2);
  float* bcat = (float*)alloc(352 * 4);
  float* bprime = (float*)alloc(256 * 4);
  float* oaf  = (float*)alloc(3600ull * 96 * 4);
  u16*  qcat  = (u16*)alloc(3600ull * 512 * 2);  // [attn | q_bf16]
  (void)ws_size; (void)in_sizes; (void)n_in; (void)out_size;

  prep_weights<<<900, 256, 0, stream>>>(Wq, Wv, Woff, Wattn, Wmo, Wo,
                                        bq, boff, battn, bmo, bo, query,
                                        bqoaT, wvT, woCat, bcat, bprime, qin);
  gemm_v<<<dim3(2, 313, 4), 256, 0, stream>>>(wvT, bev, bv, v);
  gemm_bt<GM_SPLIT><<<dim3(3, 29), 256, 0, stream>>>(
      qin, bqoaT, bcat, qcat + 256, oaf, 3600, 352, 256, 256, 0);
  sampler<<<7200, 256, 0, stream>>>(ctrl, pc, oaf, v, qcat);
  gemm_bt<GM_F32><<<dim3(2, 29), 256, 0, stream>>>(
      qcat, woCat, bprime, nullptr, (float*)d_out, 3600, 256, 512, 512, 256);
}